// Round 1
// baseline (251.122 us; speedup 1.0000x reference)
//
#include <hip/hip_runtime.h>
#include <math.h>

#define NB 4
#define NT 8192
#define ND 1024
#define NF 4096
#define NE 8

#define K1_CHB 128          // logits blocks per batch
#define K3_CHUNKS 64        // slot-partial chunks per batch
#define K3_TOK (NT / K3_CHUNKS)   // 128 tokens per block
#define K7_CHB 128
#define K7_TOK (NT / K7_CHB)      // 64 tokens per block

__device__ __forceinline__ float dot4(float4 a, float4 b) {
  return a.x * b.x + a.y * b.y + a.z * b.z + a.w * b.w;
}

// K1: logits[b,t,e] = X[b,t,:] . slots_w[e,:]
__global__ __launch_bounds__(256) void k_logits(const float* __restrict__ X,
                                                const float* __restrict__ sw,
                                                float* __restrict__ logits) {
  __shared__ float4 s_sw[NE * ND / 4];  // 32 KB
  for (int i = threadIdx.x; i < NE * ND / 4; i += 256)
    s_sw[i] = ((const float4*)sw)[i];
  __syncthreads();
  const int lane = threadIdx.x & 63;
  const int wave = threadIdx.x >> 6;
  const int b = blockIdx.x / K1_CHB;
  const int chunk = blockIdx.x % K1_CHB;
  const int t0 = chunk * (NT / K1_CHB);
  for (int tl = wave; tl < NT / K1_CHB; tl += 4) {
    const int t = t0 + tl;
    const float4* xrow = (const float4*)(X + ((size_t)b * NT + t) * ND);
    float acc[NE];
#pragma unroll
    for (int e = 0; e < NE; ++e) acc[e] = 0.f;
#pragma unroll
    for (int it = 0; it < ND / 256; ++it) {
      float4 x = xrow[it * 64 + lane];
#pragma unroll
      for (int e = 0; e < NE; ++e)
        acc[e] += dot4(x, s_sw[e * (ND / 4) + it * 64 + lane]);
    }
#pragma unroll
    for (int e = 0; e < NE; ++e)
#pragma unroll
      for (int off = 32; off > 0; off >>= 1)
        acc[e] += __shfl_xor(acc[e], off);
    if (lane == 0) {
      float* lg = logits + ((size_t)b * NT + t) * NE;
#pragma unroll
      for (int e = 0; e < NE; ++e) lg[e] = acc[e];
    }
  }
}

// K2: per (b,e) column max & sum(exp) over T  (dispatch softmax stats)
__global__ __launch_bounds__(256) void k_colstats(const float* __restrict__ logits,
                                                  float* __restrict__ M,
                                                  float* __restrict__ L) {
  const int b = blockIdx.x / NE;
  const int e = blockIdx.x % NE;
  const int tid = threadIdx.x;
  const int lane = tid & 63, wave = tid >> 6;
  const float* base = logits + (size_t)b * NT * NE + e;
  float v[NT / 256];
#pragma unroll
  for (int i = 0; i < NT / 256; ++i) v[i] = base[(size_t)(tid + i * 256) * NE];
  float mx = -1e30f;
#pragma unroll
  for (int i = 0; i < NT / 256; ++i) mx = fmaxf(mx, v[i]);
#pragma unroll
  for (int off = 32; off > 0; off >>= 1) mx = fmaxf(mx, __shfl_xor(mx, off));
  __shared__ float red[4];
  if (lane == 0) red[wave] = mx;
  __syncthreads();
  mx = fmaxf(fmaxf(red[0], red[1]), fmaxf(red[2], red[3]));
  float s = 0.f;
#pragma unroll
  for (int i = 0; i < NT / 256; ++i) s += expf(v[i] - mx);
#pragma unroll
  for (int off = 32; off > 0; off >>= 1) s += __shfl_xor(s, off);
  __syncthreads();
  if (lane == 0) red[wave] = s;
  __syncthreads();
  if (tid == 0) {
    M[blockIdx.x] = mx;
    L[blockIdx.x] = red[0] + red[1] + red[2] + red[3];
  }
}

// K3: partial exp-weighted sums of X -> partial[block][e][d]
__global__ __launch_bounds__(256) void k_slots_partial(const float* __restrict__ X,
                                                       const float* __restrict__ logits,
                                                       const float* __restrict__ M,
                                                       float* __restrict__ partial) {
  const int b = blockIdx.x / K3_CHUNKS;
  const int chunk = blockIdx.x % K3_CHUNKS;
  const int t0 = chunk * K3_TOK;
  __shared__ float pw[K3_TOK][NE];  // 4 KB
  __shared__ float sM[NE];
  if (threadIdx.x < NE) sM[threadIdx.x] = M[b * NE + threadIdx.x];
  __syncthreads();
  for (int i = threadIdx.x; i < K3_TOK * NE; i += 256) {
    const int t = i / NE, e = i % NE;
    pw[t][e] = expf(logits[((size_t)b * NT + t0 + t) * NE + e] - sM[e]);
  }
  __syncthreads();
  const int d0 = threadIdx.x * 4;
  float4 acc[NE];
#pragma unroll
  for (int e = 0; e < NE; ++e) acc[e] = make_float4(0.f, 0.f, 0.f, 0.f);
  for (int t = 0; t < K3_TOK; ++t) {
    float4 x = *(const float4*)(X + ((size_t)b * NT + t0 + t) * ND + d0);
#pragma unroll
    for (int e = 0; e < NE; ++e) {
      const float w = pw[t][e];
      acc[e].x += w * x.x; acc[e].y += w * x.y;
      acc[e].z += w * x.z; acc[e].w += w * x.w;
    }
  }
  float* pout = partial + (size_t)blockIdx.x * (NE * ND);
#pragma unroll
  for (int e = 0; e < NE; ++e)
    *(float4*)(pout + e * ND + d0) = acc[e];
}

// K4: reduce partials across chunks, normalize by L -> slots[b,e,d]
__global__ __launch_bounds__(256) void k_slots_reduce(const float* __restrict__ partial,
                                                      const float* __restrict__ L,
                                                      float* __restrict__ slots) {
  const int idx = blockIdx.x * 256 + threadIdx.x;  // < NB*NE*ND
  const int b = idx / (NE * ND);
  const int ed = idx % (NE * ND);
  const int e = ed / ND;
  float s = 0.f;
  const float* p = partial + (size_t)b * K3_CHUNKS * (NE * ND) + ed;
  for (int c = 0; c < K3_CHUNKS; ++c) s += p[(size_t)c * NE * ND];
  slots[idx] = s / L[b * NE + e];
}

// K5: h[e,f,b] = silu(slots[b,e,:].w1[e,f,:]) * (slots[b,e,:].w3[e,f,:])
__global__ __launch_bounds__(256) void k_ffn1(const float* __restrict__ slots,
                                              const float* __restrict__ w1,
                                              const float* __restrict__ w3,
                                              float* __restrict__ h) {
  const int e = blockIdx.x / (NF / 16);
  const int fc = blockIdx.x % (NF / 16);
  __shared__ float4 s_sl[NB][ND / 4];  // 16 KB
  for (int i = threadIdx.x; i < NB * ND / 4; i += 256) {
    const int b = i / (ND / 4), j = i % (ND / 4);
    s_sl[b][j] = ((const float4*)(slots + ((size_t)b * NE + e) * ND))[j];
  }
  __syncthreads();
  const int lane = threadIdx.x & 63, wave = threadIdx.x >> 6;
  for (int r = 0; r < 4; ++r) {
    const int f = fc * 16 + wave * 4 + r;
    const float4* w1r = (const float4*)(w1 + ((size_t)e * NF + f) * ND);
    const float4* w3r = (const float4*)(w3 + ((size_t)e * NF + f) * ND);
    float a1[NB], a3[NB];
#pragma unroll
    for (int b = 0; b < NB; ++b) { a1[b] = 0.f; a3[b] = 0.f; }
#pragma unroll
    for (int it = 0; it < ND / 256; ++it) {
      float4 x1 = w1r[it * 64 + lane];
      float4 x3 = w3r[it * 64 + lane];
#pragma unroll
      for (int b = 0; b < NB; ++b) {
        float4 s = s_sl[b][it * 64 + lane];
        a1[b] += dot4(x1, s);
        a3[b] += dot4(x3, s);
      }
    }
#pragma unroll
    for (int b = 0; b < NB; ++b) {
#pragma unroll
      for (int off = 32; off > 0; off >>= 1) {
        a1[b] += __shfl_xor(a1[b], off);
        a3[b] += __shfl_xor(a3[b], off);
      }
    }
    if (lane == 0) {
#pragma unroll
      for (int b = 0; b < NB; ++b) {
        const float v1 = a1[b];
        const float sil = v1 / (1.f + expf(-v1));
        h[((size_t)e * NF + f) * NB + b] = sil * a3[b];
      }
    }
  }
}

// K6: y[b,e,d] = sum_f h[e,f,b] * w2[e,d,f]
__global__ __launch_bounds__(256) void k_ffn2(const float* __restrict__ h,
                                              const float* __restrict__ w2,
                                              float* __restrict__ y) {
  const int e = blockIdx.x / (ND / 16);
  const int dc = blockIdx.x % (ND / 16);
  __shared__ float s_h[NB][NF];  // 64 KB
  for (int i = threadIdx.x; i < NF; i += 256) {
    float4 v = ((const float4*)(h + (size_t)e * NF * NB))[i];
    s_h[0][i] = v.x; s_h[1][i] = v.y; s_h[2][i] = v.z; s_h[3][i] = v.w;
  }
  __syncthreads();
  const int lane = threadIdx.x & 63, wave = threadIdx.x >> 6;
  for (int r = 0; r < 4; ++r) {
    const int d = dc * 16 + wave * 4 + r;
    const float4* w2r = (const float4*)(w2 + ((size_t)e * ND + d) * NF);
    float a[NB];
#pragma unroll
    for (int b = 0; b < NB; ++b) a[b] = 0.f;
#pragma unroll
    for (int it = 0; it < NF / 256; ++it) {
      float4 x = w2r[it * 64 + lane];
#pragma unroll
      for (int b = 0; b < NB; ++b) {
        float4 hv = *(const float4*)(&s_h[b][(it * 64 + lane) * 4]);
        a[b] += dot4(x, hv);
      }
    }
#pragma unroll
    for (int b = 0; b < NB; ++b)
#pragma unroll
      for (int off = 32; off > 0; off >>= 1) a[b] += __shfl_xor(a[b], off);
    if (lane == 0) {
#pragma unroll
      for (int b = 0; b < NB; ++b)
        y[((size_t)b * NE + e) * ND + d] = a[b];
    }
  }
}

// K7: out[b,t,d] = sum_e softmax_e(logits[b,t,:]) * y[b,e,d]
__global__ __launch_bounds__(256) void k_combine(const float* __restrict__ logits,
                                                 const float* __restrict__ y,
                                                 float* __restrict__ out) {
  const int b = blockIdx.x / K7_CHB;
  const int chunk = blockIdx.x % K7_CHB;
  const int t0 = chunk * K7_TOK;
  __shared__ float4 s_y[NE * ND / 4];  // 32 KB
  for (int i = threadIdx.x; i < NE * ND / 4; i += 256)
    s_y[i] = ((const float4*)(y + (size_t)b * NE * ND))[i];
  __shared__ float s_cw[K7_TOK][NE];  // 2 KB
  if (threadIdx.x < K7_TOK) {
    const int t = t0 + threadIdx.x;
    const float* lg = logits + ((size_t)b * NT + t) * NE;
    float l[NE];
    float mx = -1e30f;
#pragma unroll
    for (int e = 0; e < NE; ++e) { l[e] = lg[e]; mx = fmaxf(mx, l[e]); }
    float s = 0.f;
#pragma unroll
    for (int e = 0; e < NE; ++e) { l[e] = expf(l[e] - mx); s += l[e]; }
    const float inv = 1.f / s;
#pragma unroll
    for (int e = 0; e < NE; ++e) s_cw[threadIdx.x][e] = l[e] * inv;
  }
  __syncthreads();
  for (int t = 0; t < K7_TOK; ++t) {
    float4 o = make_float4(0.f, 0.f, 0.f, 0.f);
#pragma unroll
    for (int e = 0; e < NE; ++e) {
      const float c = s_cw[t][e];
      float4 yv = s_y[e * (ND / 4) + threadIdx.x];
      o.x += c * yv.x; o.y += c * yv.y; o.z += c * yv.z; o.w += c * yv.w;
    }
    ((float4*)(out + ((size_t)b * NT + t0 + t) * ND))[threadIdx.x] = o;
  }
}

extern "C" void kernel_launch(void* const* d_in, const int* in_sizes, int n_in,
                              void* d_out, int out_size, void* d_ws, size_t ws_size,
                              hipStream_t stream) {
  const float* X  = (const float*)d_in[0];
  const float* sw = (const float*)d_in[1];
  const float* w1 = (const float*)d_in[2];
  const float* w3 = (const float*)d_in[3];
  const float* w2 = (const float*)d_in[4];
  float* out = (float*)d_out;

  float* ws = (float*)d_ws;
  float* logits  = ws;                                        // NB*NT*NE
  float* M       = logits + (size_t)NB * NT * NE;             // NB*NE
  float* L       = M + NB * NE;                               // NB*NE
  float* partial = L + NB * NE;                               // NB*K3_CHUNKS*NE*ND
  float* slots   = partial + (size_t)NB * K3_CHUNKS * NE * ND;// NB*NE*ND
  float* h       = slots + NB * NE * ND;                      // NE*NF*NB
  float* y       = h + (size_t)NE * NF * NB;                  // NB*NE*ND

  hipLaunchKernelGGL(k_logits, dim3(NB * K1_CHB), dim3(256), 0, stream, X, sw, logits);
  hipLaunchKernelGGL(k_colstats, dim3(NB * NE), dim3(256), 0, stream, logits, M, L);
  hipLaunchKernelGGL(k_slots_partial, dim3(NB * K3_CHUNKS), dim3(256), 0, stream,
                     X, logits, M, partial);
  hipLaunchKernelGGL(k_slots_reduce, dim3(NB * NE * ND / 256), dim3(256), 0, stream,
                     partial, L, slots);
  hipLaunchKernelGGL(k_ffn1, dim3(NE * (NF / 16)), dim3(256), 0, stream, slots, w1, w3, h);
  hipLaunchKernelGGL(k_ffn2, dim3(NE * (ND / 16)), dim3(256), 0, stream, h, w2, y);
  hipLaunchKernelGGL(k_combine, dim3(NB * K7_CHB), dim3(256), 0, stream, logits, y, out);
}

// Round 2
// 211.967 us; speedup vs baseline: 1.1847x; 1.1847x over previous
//
#include <hip/hip_runtime.h>
#include <math.h>

#define NB 4
#define NT 8192
#define ND 1024
#define NF 4096
#define NE 8

#define K1_CHB 128
#define K3_CHUNKS 64
#define K3_TOK 128
#define K3_TT 8
#define K3_TILES (K3_TOK / K3_TT)   // 16
#define K7_CHB 128
#define K7_TOK (NT / K7_CHB)        // 64

#define F1_TILE 4
#define F1_ROWS 64
#define F1_TILES (F1_ROWS / F1_TILE) // 16
#define F2_DR 8

#define CFENCE() asm volatile("" ::: "memory")

__device__ __forceinline__ float dot4(float4 a, float4 b) {
  return a.x * b.x + a.y * b.y + a.z * b.z + a.w * b.w;
}

__device__ __forceinline__ void gload16(const void* g, void* l) {
  __builtin_amdgcn_global_load_lds((const __attribute__((address_space(1))) void*)g,
                                   (__attribute__((address_space(3))) void*)l,
                                   16, 0, 0);
}

// Value-splitting butterfly: sums 8 per-lane partials over 64 lanes in 10
// shuffles. Returns, in each lane, the total of v[id] where id = lane & 7
// (id bit0=lane bit0, bit1=lane bit1, bit2=lane bit2).
__device__ __forceinline__ float reduce8(float v0, float v1, float v2, float v3,
                                         float v4, float v5, float v6, float v7,
                                         int lane) {
  const bool b0 = lane & 1;
  float s, u0, u1, u2, u3;
  s = b0 ? v0 : v1; u0 = (b0 ? v1 : v0) + __shfl_xor(s, 1);
  s = b0 ? v2 : v3; u1 = (b0 ? v3 : v2) + __shfl_xor(s, 1);
  s = b0 ? v4 : v5; u2 = (b0 ? v5 : v4) + __shfl_xor(s, 1);
  s = b0 ? v6 : v7; u3 = (b0 ? v7 : v6) + __shfl_xor(s, 1);
  const bool b1 = lane & 2;
  float w0, w1;
  s = b1 ? u0 : u1; w0 = (b1 ? u1 : u0) + __shfl_xor(s, 2);
  s = b1 ? u2 : u3; w1 = (b1 ? u3 : u2) + __shfl_xor(s, 2);
  const bool b2 = lane & 4;
  s = b2 ? w0 : w1; float x = (b2 ? w1 : w0) + __shfl_xor(s, 4);
  x += __shfl_xor(x, 8);
  x += __shfl_xor(x, 16);
  x += __shfl_xor(x, 32);
  return x;
}

// K1: logits[b,t,e] = X[b,t,:] . slots_w[e,:]
__global__ __launch_bounds__(256) void k_logits(const float* __restrict__ X,
                                                const float* __restrict__ sw,
                                                float* __restrict__ logits) {
  __shared__ float4 s_sw[NE * ND / 4];  // 32 KB
  for (int i = threadIdx.x; i < NE * ND / 4; i += 256)
    s_sw[i] = ((const float4*)sw)[i];
  __syncthreads();
  const int lane = threadIdx.x & 63;
  const int wave = threadIdx.x >> 6;
  const int b = blockIdx.x / K1_CHB;
  const int chunk = blockIdx.x % K1_CHB;
  const int t0 = chunk * (NT / K1_CHB);
  for (int tl = wave; tl < NT / K1_CHB; tl += 4) {
    const int t = t0 + tl;
    const float4* xrow = (const float4*)(X + ((size_t)b * NT + t) * ND);
    float acc[NE];
#pragma unroll
    for (int e = 0; e < NE; ++e) acc[e] = 0.f;
#pragma unroll
    for (int it = 0; it < ND / 256; ++it) {
      float4 x = xrow[it * 64 + lane];
#pragma unroll
      for (int e = 0; e < NE; ++e)
        acc[e] += dot4(x, s_sw[e * (ND / 4) + it * 64 + lane]);
    }
    float r = reduce8(acc[0], acc[1], acc[2], acc[3],
                      acc[4], acc[5], acc[6], acc[7], lane);
    if (lane < 8) logits[((size_t)b * NT + t) * NE + lane] = r;
  }
}

// K2: per (b,e) column max & sum(exp) over T
__global__ __launch_bounds__(256) void k_colstats(const float* __restrict__ logits,
                                                  float* __restrict__ M,
                                                  float* __restrict__ L) {
  const int b = blockIdx.x / NE;
  const int e = blockIdx.x % NE;
  const int tid = threadIdx.x;
  const int lane = tid & 63, wave = tid >> 6;
  const float* base = logits + (size_t)b * NT * NE + e;
  float v[NT / 256];
#pragma unroll
  for (int i = 0; i < NT / 256; ++i) v[i] = base[(size_t)(tid + i * 256) * NE];
  float mx = -1e30f;
#pragma unroll
  for (int i = 0; i < NT / 256; ++i) mx = fmaxf(mx, v[i]);
#pragma unroll
  for (int off = 32; off > 0; off >>= 1) mx = fmaxf(mx, __shfl_xor(mx, off));
  __shared__ float red[4];
  if (lane == 0) red[wave] = mx;
  __syncthreads();
  mx = fmaxf(fmaxf(red[0], red[1]), fmaxf(red[2], red[3]));
  float s = 0.f;
#pragma unroll
  for (int i = 0; i < NT / 256; ++i) s += expf(v[i] - mx);
#pragma unroll
  for (int off = 32; off > 0; off >>= 1) s += __shfl_xor(s, off);
  __syncthreads();
  if (lane == 0) red[wave] = s;
  __syncthreads();
  if (tid == 0) {
    M[blockIdx.x] = mx;
    L[blockIdx.x] = red[0] + red[1] + red[2] + red[3];
  }
}

// K3: partial exp-weighted sums of X -> partial[block][e][d]
// LDS-staged X tiles (8 tokens = 32KB), double-buffered, counted vmcnt.
__global__ __launch_bounds__(256, 1) void k_slots_partial(const float* __restrict__ X,
                                                          const float* __restrict__ logits,
                                                          const float* __restrict__ M,
                                                          float* __restrict__ partial) {
  __shared__ float xt[2][K3_TT][ND];   // 64 KB
  __shared__ float pw[K3_TOK][NE];     // 4 KB
  __shared__ float sM[NE];
  const int tid = threadIdx.x;
  const int b = blockIdx.x / K3_CHUNKS;
  const int chunk = blockIdx.x % K3_CHUNKS;
  const int t0 = chunk * K3_TOK;
  if (tid < NE) sM[tid] = M[b * NE + tid];
  __syncthreads();
  for (int i = tid; i < K3_TOK * NE; i += 256) {
    const int t = i >> 3, e = i & 7;
    pw[t][e] = expf(logits[((size_t)b * NT + t0 + t) * NE + e] - sM[e]);
  }
  const char* xbase = (const char*)(X + ((size_t)b * NT + t0) * ND);
  auto stage = [&](int buf, int t) {
#pragma unroll
    for (int r = 0; r < 8; ++r) {
      const int o = r * 4096 + tid * 16;
      gload16(xbase + (size_t)t * (K3_TT * ND * 4) + o, ((char*)&xt[buf][0][0]) + o);
    }
  };
  stage(0, 0);
  __syncthreads();  // pw + sM visible; drains stage(0) too (prologue only)

  float4 acc[NE];
#pragma unroll
  for (int e = 0; e < NE; ++e) acc[e] = make_float4(0.f, 0.f, 0.f, 0.f);

  for (int t = 0; t < K3_TILES; ++t) {
    const int cur = t & 1;
    if (t > 0) { CFENCE(); __builtin_amdgcn_s_barrier(); }
    if (t + 1 < K3_TILES) {
      stage(cur ^ 1, t + 1);
      asm volatile("s_waitcnt vmcnt(8)" ::: "memory");
    } else {
      asm volatile("s_waitcnt vmcnt(0)" ::: "memory");
    }
    __builtin_amdgcn_s_barrier();
    CFENCE();
#pragma unroll
    for (int tk = 0; tk < K3_TT; ++tk) {
      float4 x4 = *(const float4*)&xt[cur][tk][tid * 4];
      const float* pwr = &pw[t * K3_TT + tk][0];
#pragma unroll
      for (int e = 0; e < NE; ++e) {
        const float w = pwr[e];
        acc[e].x += w * x4.x; acc[e].y += w * x4.y;
        acc[e].z += w * x4.z; acc[e].w += w * x4.w;
      }
    }
  }
  float* pout = partial + (size_t)blockIdx.x * (NE * ND);
#pragma unroll
  for (int e = 0; e < NE; ++e)
    *(float4*)(pout + e * ND + tid * 4) = acc[e];
}

// K4: reduce partials across chunks, normalize by L -> slots[b,e,d]
__global__ __launch_bounds__(256) void k_slots_reduce(const float* __restrict__ partial,
                                                      const float* __restrict__ L,
                                                      float* __restrict__ slots) {
  const int idx = blockIdx.x * 256 + threadIdx.x;
  const int b = idx / (NE * ND);
  const int ed = idx % (NE * ND);
  const int e = ed / ND;
  float s = 0.f;
  const float* p = partial + (size_t)b * K3_CHUNKS * (NE * ND) + ed;
  for (int c = 0; c < K3_CHUNKS; ++c) s += p[(size_t)c * NE * ND];
  slots[idx] = s / L[b * NE + e];
}

// K5: h[e,b,f] = silu(slots[b,e,:].w1[e,f,:]) * (slots[b,e,:].w3[e,f,:])
// Tiles of 4 f-rows from w1+w3 (32KB), dbuf, gload_lds, counted vmcnt.
__global__ __launch_bounds__(256, 2) void k_ffn1(const float* __restrict__ slots,
                                                 const float* __restrict__ w1,
                                                 const float* __restrict__ w3,
                                                 float* __restrict__ h) {
  __shared__ float lds[2][2][F1_TILE][ND];  // 64 KB
  __shared__ float4 s_sl[NB][ND / 4];       // 16 KB
  const int tid = threadIdx.x;
  const int lane = tid & 63, wave = tid >> 6;
  const int e = blockIdx.x / (NF / F1_ROWS);
  const int f0 = (blockIdx.x % (NF / F1_ROWS)) * F1_ROWS;

  for (int i = tid; i < NB * ND / 4; i += 256) {
    const int b = i / (ND / 4), j = i % (ND / 4);
    s_sl[b][j] = ((const float4*)(slots + ((size_t)b * NE + e) * ND))[j];
  }

  const char* w1base = (const char*)(w1 + ((size_t)e * NF + f0) * ND);
  const char* w3base = (const char*)(w3 + ((size_t)e * NF + f0) * ND);
  auto stage = [&](int buf, int t) {
    const size_t gb = (size_t)t * (F1_TILE * ND * 4);
#pragma unroll
    for (int r = 0; r < 4; ++r) {
      const int o = r * 4096 + tid * 16;
      gload16(w1base + gb + o, ((char*)&lds[buf][0][0][0]) + o);
      gload16(w3base + gb + o, ((char*)&lds[buf][1][0][0]) + o);
    }
  };
  stage(0, 0);
  __syncthreads();  // slots visible; drains stage(0) (prologue only)

  for (int t = 0; t < F1_TILES; ++t) {
    const int cur = t & 1;
    if (t > 0) { CFENCE(); __builtin_amdgcn_s_barrier(); }
    if (t + 1 < F1_TILES) {
      stage(cur ^ 1, t + 1);
      asm volatile("s_waitcnt vmcnt(8)" ::: "memory");
    } else {
      asm volatile("s_waitcnt vmcnt(0)" ::: "memory");
    }
    __builtin_amdgcn_s_barrier();
    CFENCE();
    const float4* r1 = (const float4*)&lds[cur][0][wave][0];
    const float4* r3 = (const float4*)&lds[cur][1][wave][0];
    float a1[NB] = {0.f, 0.f, 0.f, 0.f}, a3[NB] = {0.f, 0.f, 0.f, 0.f};
#pragma unroll
    for (int it = 0; it < 4; ++it) {
      float4 wv1 = r1[it * 64 + lane];
      float4 wv3 = r3[it * 64 + lane];
#pragma unroll
      for (int b = 0; b < NB; ++b) {
        float4 sv = s_sl[b][it * 64 + lane];
        a1[b] += dot4(wv1, sv);
        a3[b] += dot4(wv3, sv);
      }
    }
    float x = reduce8(a1[0], a1[1], a1[2], a1[3],
                      a3[0], a3[1], a3[2], a3[3], lane);
    float other = __shfl_xor(x, 4);  // a3 partner for a1 holders
    if (lane < 4) {
      const int f = f0 + t * F1_TILE + wave;
      const float sil = x / (1.f + expf(-x));
      h[((size_t)e * NB + lane) * NF + f] = sil * other;
    }
  }
}

// K6: y[b,e,d] = sum_f h[e,b,f] * w2[e,d,f]
// h e-slice (64KB) staged once; w2 tiles 8 rows x 1024 f-chunk, dbuf.
__global__ __launch_bounds__(256, 1) void k_ffn2(const float* __restrict__ h,
                                                 const float* __restrict__ w2,
                                                 float* __restrict__ y) {
  __shared__ float s_h[NB][NF];           // 64 KB  [b][f]
  __shared__ float tile[2][F2_DR][1024];  // 64 KB
  const int tid = threadIdx.x;
  const int lane = tid & 63, wave = tid >> 6;
  const int e = blockIdx.x / (ND / F2_DR);
  const int d0 = (blockIdx.x % (ND / F2_DR)) * F2_DR;

  const char* hbase = (const char*)(h + (size_t)e * NB * NF);
#pragma unroll
  for (int r = 0; r < 16; ++r) {
    const int o = r * 4096 + tid * 16;
    gload16(hbase + o, ((char*)&s_h[0][0]) + o);
  }
  const char* w2base = (const char*)(w2 + ((size_t)e * ND + d0) * NF);
  auto stage = [&](int buf, int c) {
#pragma unroll
    for (int r = 0; r < F2_DR; ++r) {
      const int o = tid * 16;
      gload16(w2base + (size_t)r * (NF * 4) + c * 4096 + o,
              ((char*)&tile[buf][r][0]) + o);
    }
  };
  stage(0, 0);

  float a0[NB] = {0.f, 0.f, 0.f, 0.f}, a1v[NB] = {0.f, 0.f, 0.f, 0.f};
  for (int c = 0; c < 4; ++c) {
    const int cur = c & 1;
    if (c > 0) { CFENCE(); __builtin_amdgcn_s_barrier(); }
    if (c + 1 < 4) {
      stage(cur ^ 1, c + 1);
      asm volatile("s_waitcnt vmcnt(8)" ::: "memory");
    } else {
      asm volatile("s_waitcnt vmcnt(0)" ::: "memory");
    }
    __builtin_amdgcn_s_barrier();
    CFENCE();
    const float4* r0 = (const float4*)&tile[cur][wave * 2][0];
    const float4* r1 = (const float4*)&tile[cur][wave * 2 + 1][0];
    const float4* hb0 = (const float4*)&s_h[0][c * 1024];
    const float4* hb1 = (const float4*)&s_h[1][c * 1024];
    const float4* hb2 = (const float4*)&s_h[2][c * 1024];
    const float4* hb3 = (const float4*)&s_h[3][c * 1024];
#pragma unroll
    for (int it = 0; it < 4; ++it) {
      const int j = it * 64 + lane;
      float4 w0 = r0[j], w1v = r1[j];
      float4 h0 = hb0[j], h1 = hb1[j], h2 = hb2[j], h3 = hb3[j];
      a0[0] += dot4(w0, h0); a0[1] += dot4(w0, h1);
      a0[2] += dot4(w0, h2); a0[3] += dot4(w0, h3);
      a1v[0] += dot4(w1v, h0); a1v[1] += dot4(w1v, h1);
      a1v[2] += dot4(w1v, h2); a1v[3] += dot4(w1v, h3);
    }
  }
  float x = reduce8(a0[0], a0[1], a0[2], a0[3],
                    a1v[0], a1v[1], a1v[2], a1v[3], lane);
  if (lane < 8) {
    const int b = lane & 3, rr = (lane >> 2) & 1;
    y[((size_t)b * NE + e) * ND + d0 + wave * 2 + rr] = x;
  }
}

// K7: out[b,t,d] = sum_e softmax_e(logits[b,t,:]) * y[b,e,d]
__global__ __launch_bounds__(256) void k_combine(const float* __restrict__ logits,
                                                 const float* __restrict__ y,
                                                 float* __restrict__ out) {
  const int b = blockIdx.x / K7_CHB;
  const int chunk = blockIdx.x % K7_CHB;
  const int t0 = chunk * K7_TOK;
  __shared__ float4 s_y[NE * ND / 4];  // 32 KB
  for (int i = threadIdx.x; i < NE * ND / 4; i += 256)
    s_y[i] = ((const float4*)(y + (size_t)b * NE * ND))[i];
  __shared__ float s_cw[K7_TOK][NE];
  if (threadIdx.x < K7_TOK) {
    const int t = t0 + threadIdx.x;
    const float* lg = logits + ((size_t)b * NT + t) * NE;
    float l[NE];
    float mx = -1e30f;
#pragma unroll
    for (int e = 0; e < NE; ++e) { l[e] = lg[e]; mx = fmaxf(mx, l[e]); }
    float s = 0.f;
#pragma unroll
    for (int e = 0; e < NE; ++e) { l[e] = expf(l[e] - mx); s += l[e]; }
    const float inv = 1.f / s;
#pragma unroll
    for (int e = 0; e < NE; ++e) s_cw[threadIdx.x][e] = l[e] * inv;
  }
  __syncthreads();
  for (int t = 0; t < K7_TOK; ++t) {
    float4 o = make_float4(0.f, 0.f, 0.f, 0.f);
#pragma unroll
    for (int e = 0; e < NE; ++e) {
      const float c = s_cw[t][e];
      float4 yv = s_y[e * (ND / 4) + threadIdx.x];
      o.x += c * yv.x; o.y += c * yv.y; o.z += c * yv.z; o.w += c * yv.w;
    }
    ((float4*)(out + ((size_t)b * NT + t0 + t) * ND))[threadIdx.x] = o;
  }
}

extern "C" void kernel_launch(void* const* d_in, const int* in_sizes, int n_in,
                              void* d_out, int out_size, void* d_ws, size_t ws_size,
                              hipStream_t stream) {
  const float* X  = (const float*)d_in[0];
  const float* sw = (const float*)d_in[1];
  const float* w1 = (const float*)d_in[2];
  const float* w3 = (const float*)d_in[3];
  const float* w2 = (const float*)d_in[4];
  float* out = (float*)d_out;

  float* ws = (float*)d_ws;
  float* logits  = ws;                                         // NB*NT*NE
  float* M       = logits + (size_t)NB * NT * NE;              // NB*NE
  float* L       = M + NB * NE;                                // NB*NE
  float* partial = L + NB * NE;                                // NB*K3_CHUNKS*NE*ND
  float* slots   = partial + (size_t)NB * K3_CHUNKS * NE * ND; // NB*NE*ND
  float* h       = slots + NB * NE * ND;                       // NE*NB*NF
  float* y       = h + (size_t)NE * NB * NF;                   // NB*NE*ND

  hipLaunchKernelGGL(k_logits, dim3(NB * K1_CHB), dim3(256), 0, stream, X, sw, logits);
  hipLaunchKernelGGL(k_colstats, dim3(NB * NE), dim3(256), 0, stream, logits, M, L);
  hipLaunchKernelGGL(k_slots_partial, dim3(NB * K3_CHUNKS), dim3(256), 0, stream,
                     X, logits, M, partial);
  hipLaunchKernelGGL(k_slots_reduce, dim3(NB * NE * ND / 256), dim3(256), 0, stream,
                     partial, L, slots);
  hipLaunchKernelGGL(k_ffn1, dim3(NE * (NF / F1_ROWS)), dim3(256), 0, stream,
                     slots, w1, w3, h);
  hipLaunchKernelGGL(k_ffn2, dim3(NE * (ND / F2_DR)), dim3(256), 0, stream, h, w2, y);
  hipLaunchKernelGGL(k_combine, dim3(NB * K7_CHB), dim3(256), 0, stream, logits, y, out);
}